// Round 1
// baseline (1745.098 us; speedup 1.0000x reference)
//
#include <hip/hip_runtime.h>
#include <stdint.h>

#define D 128
#define TR 32   // rows per block in fused_linear; 100000%32==0, 200000%32==0

// ---------------------------------------------------------------------------
// deg histogram (int atomics, ~1.2M total)
// ---------------------------------------------------------------------------
__global__ void count_deg_kernel(const int* __restrict__ ea, const int* __restrict__ ep,
                                 int E, int* __restrict__ degA, int* __restrict__ degP) {
    int stride = gridDim.x * blockDim.x;
    for (int e = blockIdx.x * blockDim.x + threadIdx.x; e < E; e += stride) {
        atomicAdd(&degA[ea[e]], 1);
        atomicAdd(&degP[ep[e]], 1);
    }
}

// ---------------------------------------------------------------------------
// exclusive scan of deg -> row_start (rs) and cursor copy (cur).
// One block per array (grid=2), 256 threads, per-thread contiguous segment +
// block-level Hillis-Steele over segment sums. Writes rs[n] = total (=E).
// ---------------------------------------------------------------------------
__global__ void scan_kernel(const int* degA, int nA, int* rsA, int* curA,
                            const int* degP, int nP, int* rsP, int* curP) {
    const int* deg; int n; int* rs; int* cur;
    if (blockIdx.x == 0) { deg = degA; n = nA; rs = rsA; cur = curA; }
    else                 { deg = degP; n = nP; rs = rsP; cur = curP; }

    int tid = threadIdx.x;
    int per = (n + 255) >> 8;
    int lo = tid * per; if (lo > n) lo = n;
    int hi = lo + per;  if (hi > n) hi = n;

    int local = 0;
    for (int i = lo; i < hi; ++i) local += deg[i];

    __shared__ int sums[256];
    sums[tid] = local;
    __syncthreads();
    for (int off = 1; off < 256; off <<= 1) {
        int v = (tid >= off) ? sums[tid - off] : 0;
        __syncthreads();
        sums[tid] += v;
        __syncthreads();
    }
    int run = (tid == 0) ? 0 : sums[tid - 1];
    for (int i = lo; i < hi; ++i) {
        rs[i] = run; cur[i] = run; run += deg[i];
    }
    if (hi == n) rs[n] = run;  // all writers write the same total
}

// ---------------------------------------------------------------------------
// CSR fill via atomic cursors (order within a row is arbitrary; sum is a sum)
// csrA: rows=authors, entries=paper srcs.  csrP: rows=papers, entries=author srcs.
// ---------------------------------------------------------------------------
__global__ void csr_fill_kernel(const int* __restrict__ ea, const int* __restrict__ ep, int E,
                                int* __restrict__ curA, int* __restrict__ curP,
                                int* __restrict__ csrA, int* __restrict__ csrP) {
    int stride = gridDim.x * blockDim.x;
    for (int e = blockIdx.x * blockDim.x + threadIdx.x; e < E; e += stride) {
        int a = ea[e], p = ep[e];
        int sa = atomicAdd(&curA[a], 1);
        csrA[sa] = p;
        int sp = atomicAdd(&curP[p], 1);
        csrP[sp] = a;
    }
}

// ---------------------------------------------------------------------------
// pull-mode aggregation: one wave per dst row; lane covers 2 floats.
// agg[d] = sum_{j in row d} xsrc[csr[j]]   (no atomics, no zero-init needed)
// ---------------------------------------------------------------------------
__global__ __launch_bounds__(256) void aggregate_kernel(
        const float* __restrict__ xsrc, const int* __restrict__ rs,
        const int* __restrict__ csr, int ndst, float* __restrict__ agg) {
    int gw   = (blockIdx.x * 256 + threadIdx.x) >> 6;
    int lane = threadIdx.x & 63;
    int nw   = (gridDim.x * 256) >> 6;
    for (int d = gw; d < ndst; d += nw) {
        int s0 = rs[d], s1 = rs[d + 1];
        float2 acc = make_float2(0.f, 0.f);
        for (int j = s0; j < s1; ++j) {
            int s = csr[j];
            float2 v = *(const float2*)(xsrc + (size_t)s * D + lane * 2);
            acc.x += v.x; acc.y += v.y;
        }
        *(float2*)(agg + (size_t)d * D + lane * 2) = acc;
    }
}

// ---------------------------------------------------------------------------
// fused node update: out = maybe_relu( xs@Ws + xm@Wm + bs + deg*bm )
// Block: 32 rows x 128 cols. x tiles staged in LDS (32KB); W streamed from L2.
// Thread computes a 4x4 register tile; k unrolled by 2 (float2 LDS reads).
// NOTE: out may alias xm (in-place): each block stages its own rows into LDS
// before any write, and rows are block-exclusive. xm/out NOT __restrict__.
// ---------------------------------------------------------------------------
__global__ __launch_bounds__(256) void fused_linear_kernel(
        const float* __restrict__ xs, const float* xm,
        const float* __restrict__ Ws, const float* __restrict__ Wm,
        const float* __restrict__ bs, const float* __restrict__ bm,
        const int* __restrict__ deg, int relu, float* out) {
    __shared__ float lxs[TR][D];
    __shared__ float lxm[TR][D];
    int tid = threadIdx.x;
    int r_base = blockIdx.x * TR;

    const float4* xs4 = (const float4*)(xs + (size_t)r_base * D);
    const float4* xm4 = (const float4*)(xm + (size_t)r_base * D);
#pragma unroll
    for (int i = 0; i < 4; ++i) {
        int idx = i * 256 + tid;          // 0..1023 float4s (32 rows x 32 f4)
        int r = idx >> 5, c4 = idx & 31;
        *(float4*)&lxs[r][c4 * 4] = xs4[idx];
        *(float4*)&lxm[r][c4 * 4] = xm4[idx];
    }
    __syncthreads();

    int c0 = (tid & 31) * 4;       // output col group
    int r0 = (tid >> 5) * 4;       // output row group (0..28)
    float acc[4][4] = {};

    for (int k = 0; k < D; k += 2) {
        float4 ws0 = *(const float4*)(Ws + (size_t)k * D + c0);
        float4 ws1 = *(const float4*)(Ws + (size_t)(k + 1) * D + c0);
        float4 wm0 = *(const float4*)(Wm + (size_t)k * D + c0);
        float4 wm1 = *(const float4*)(Wm + (size_t)(k + 1) * D + c0);
#pragma unroll
        for (int i = 0; i < 4; ++i) {
            float2 a = *(const float2*)&lxs[r0 + i][k];
            float2 b = *(const float2*)&lxm[r0 + i][k];
            acc[i][0] += a.x * ws0.x + a.y * ws1.x + b.x * wm0.x + b.y * wm1.x;
            acc[i][1] += a.x * ws0.y + a.y * ws1.y + b.x * wm0.y + b.y * wm1.y;
            acc[i][2] += a.x * ws0.z + a.y * ws1.z + b.x * wm0.z + b.y * wm1.z;
            acc[i][3] += a.x * ws0.w + a.y * ws1.w + b.x * wm0.w + b.y * wm1.w;
        }
    }

    float4 bsv = *(const float4*)(bs + c0);
    float4 bmv = *(const float4*)(bm + c0);
#pragma unroll
    for (int i = 0; i < 4; ++i) {
        int r = r_base + r0 + i;
        float dg = (float)deg[r];
        float4 o;
        o.x = acc[i][0] + bsv.x + dg * bmv.x;
        o.y = acc[i][1] + bsv.y + dg * bmv.y;
        o.z = acc[i][2] + bsv.z + dg * bmv.z;
        o.w = acc[i][3] + bsv.w + dg * bmv.w;
        if (relu) {
            o.x = fmaxf(o.x, 0.f); o.y = fmaxf(o.y, 0.f);
            o.z = fmaxf(o.z, 0.f); o.w = fmaxf(o.w, 0.f);
        }
        *(float4*)(out + (size_t)r * D + c0) = o;
    }
}

// ---------------------------------------------------------------------------
// supervision dot products: one wave per pair, shfl reduction
// ---------------------------------------------------------------------------
__global__ __launch_bounds__(256) void dot_kernel(
        const float* __restrict__ za, const float* __restrict__ zp,
        const int* __restrict__ sa, const int* __restrict__ sp, int S,
        float* __restrict__ out) {
    int gw   = (blockIdx.x * 256 + threadIdx.x) >> 6;
    int lane = threadIdx.x & 63;
    int nw   = (gridDim.x * 256) >> 6;
    for (int i = gw; i < S; i += nw) {
        int a = sa[i], p = sp[i];
        float2 va = *(const float2*)(za + (size_t)a * D + lane * 2);
        float2 vp = *(const float2*)(zp + (size_t)p * D + lane * 2);
        float s = va.x * vp.x + va.y * vp.y;
#pragma unroll
        for (int off = 32; off > 0; off >>= 1) s += __shfl_xor(s, off);
        if (lane == 0) out[i] = s;
    }
}

// ---------------------------------------------------------------------------
extern "C" void kernel_launch(void* const* d_in, const int* in_sizes, int n_in,
                              void* d_out, int out_size, void* d_ws, size_t ws_size,
                              hipStream_t stream) {
    const float* x_a  = (const float*)d_in[0];
    const float* x_p  = (const float*)d_in[1];
    const int*   ea   = (const int*)d_in[2];
    const int*   ep   = (const int*)d_in[3];
    const int*   sa   = (const int*)d_in[4];
    const int*   sp   = (const int*)d_in[5];
    const float* WsA  = (const float*)d_in[6];
    const float* bsA  = (const float*)d_in[7];
    const float* WsP  = (const float*)d_in[8];
    const float* bsP  = (const float*)d_in[9];
    const float* Wa2p = (const float*)d_in[10];
    const float* ba2p = (const float*)d_in[11];
    const float* Wp2a = (const float*)d_in[12];
    const float* bp2a = (const float*)d_in[13];

    const int nA = in_sizes[0] / D;   // 100000
    const int nP = in_sizes[1] / D;   // 200000
    const int E  = in_sizes[2];       // 600000
    const int S  = in_sizes[4];       // 100000

    // ---- workspace layout (~315 MB total) ----
    char* ws = (char*)d_ws;
    size_t curoff = 0;
    auto alloc = [&](size_t bytes) -> void* {
        void* p = ws + curoff;
        curoff = (curoff + bytes + 255) & ~(size_t)255;
        return p;
    };
    float* agg_a = (float*)alloc((size_t)nA * D * 4);
    float* agg_p = (float*)alloc((size_t)nP * D * 4);
    float* y_a   = (float*)alloc((size_t)nA * D * 4);
    float* y_p   = (float*)alloc((size_t)nP * D * 4);
    int* degA = (int*)alloc((size_t)nA * 4);
    int* degP = (int*)alloc((size_t)nP * 4);
    int* rsA  = (int*)alloc(((size_t)nA + 1) * 4);
    int* rsP  = (int*)alloc(((size_t)nP + 1) * 4);
    int* curA = (int*)alloc((size_t)nA * 4);
    int* curP = (int*)alloc((size_t)nP * 4);
    int* csrA = (int*)alloc((size_t)E * 4);
    int* csrP = (int*)alloc((size_t)E * 4);

    // ---- graph preprocessing (reused by both layers) ----
    size_t deg_bytes = (size_t)((char*)degP - (char*)degA) + (size_t)nP * 4;
    hipMemsetAsync(degA, 0, deg_bytes, stream);
    count_deg_kernel<<<1024, 256, 0, stream>>>(ea, ep, E, degA, degP);
    scan_kernel<<<2, 256, 0, stream>>>(degA, nA, rsA, curA, degP, nP, rsP, curP);
    csr_fill_kernel<<<1024, 256, 0, stream>>>(ea, ep, E, curA, curP, csrA, csrP);

    // ---- layer 0 (relu) ----
    aggregate_kernel<<<(nA + 3) / 4, 256, 0, stream>>>(x_p, rsA, csrA, nA, agg_a);
    aggregate_kernel<<<(nP + 3) / 4, 256, 0, stream>>>(x_a, rsP, csrP, nP, agg_p);
    fused_linear_kernel<<<nA / TR, 256, 0, stream>>>(x_a, agg_a, WsA, Wp2a, bsA, bp2a, degA, 1, y_a);
    fused_linear_kernel<<<nP / TR, 256, 0, stream>>>(x_p, agg_p, WsP, Wa2p, bsP, ba2p, degP, 1, y_p);

    // ---- layer 1 (no relu); matmul writes in-place over agg ----
    aggregate_kernel<<<(nA + 3) / 4, 256, 0, stream>>>(y_p, rsA, csrA, nA, agg_a);
    aggregate_kernel<<<(nP + 3) / 4, 256, 0, stream>>>(y_a, rsP, csrP, nP, agg_p);
    fused_linear_kernel<<<nA / TR, 256, 0, stream>>>(y_a, agg_a, WsA + D * D, Wp2a + D * D,
                                                     bsA + D, bp2a + D, degA, 0, agg_a);
    fused_linear_kernel<<<nP / TR, 256, 0, stream>>>(y_p, agg_p, WsP + D * D, Wa2p + D * D,
                                                     bsP + D, ba2p + D, degP, 0, agg_p);

    // ---- supervision scores ----
    dot_kernel<<<(S + 3) / 4, 256, 0, stream>>>(agg_a, agg_p, sa, sp, S, (float*)d_out);
}

// Round 2
// 1296.028 us; speedup vs baseline: 1.3465x; 1.3465x over previous
//
#include <hip/hip_runtime.h>
#include <stdint.h>

#define D 128
#define TR 32        // rows per block in fused_linear; 100000%32==0, 200000%32==0
#define SCAN_TILE 1024  // elements per scan block (256 thr x 4)

// ---------------------------------------------------------------------------
// deg histogram (int atomics, ~1.2M total)
// ---------------------------------------------------------------------------
__global__ void count_deg_kernel(const int* __restrict__ ea, const int* __restrict__ ep,
                                 int E, int* __restrict__ degA, int* __restrict__ degP) {
    int stride = gridDim.x * blockDim.x;
    for (int e = blockIdx.x * blockDim.x + threadIdx.x; e < E; e += stride) {
        atomicAdd(&degA[ea[e]], 1);
        atomicAdd(&degP[ep[e]], 1);
    }
}

// ---------------------------------------------------------------------------
// 3-pass device-wide exclusive scan over BOTH deg arrays in one grid.
// Blocks [0,gA) handle degA tiles, [gA,gA+gP) handle degP tiles.
// Constraint: gA+gP <= 1024 (i.e. nA+nP <= ~1M elements) — holds (300k).
// ---------------------------------------------------------------------------

// pass 1: per-block sums
__global__ __launch_bounds__(256) void scan_partials_kernel(
        const int* __restrict__ degA, int nA,
        const int* __restrict__ degP, int nP, int gA,
        int* __restrict__ partials) {
    const int* deg; int n;
    int b = blockIdx.x;
    if (b < gA) { deg = degA; n = nA; }
    else        { deg = degP; n = nP; b -= gA; }
    int tid = threadIdx.x;
    int i0 = b * SCAN_TILE + tid * 4;
    int s = 0;
    if (i0 + 3 < n) {
        int4 d = *(const int4*)(deg + i0);
        s = d.x + d.y + d.z + d.w;
    } else {
        for (int j = 0; j < 4; ++j) if (i0 + j < n) s += deg[i0 + j];
    }
#pragma unroll
    for (int off = 32; off; off >>= 1) s += __shfl_xor(s, off);
    __shared__ int wsum[4];
    if ((tid & 63) == 0) wsum[tid >> 6] = s;
    __syncthreads();
    if (tid == 0) partials[blockIdx.x] = wsum[0] + wsum[1] + wsum[2] + wsum[3];
}

// pass 2: segmented exclusive scan of partials (one 1024-thread block);
// also writes rs[n] totals for both arrays.
__global__ __launch_bounds__(1024) void scan_block_sums_kernel(
        int* __restrict__ partials, int gA, int gP,
        int* __restrict__ rsA_end, int* __restrict__ rsP_end) {
    __shared__ int s[1024];
    int n = gA + gP;
    int tid = threadIdx.x;
    int v = (tid < n) ? partials[tid] : 0;
    s[tid] = v;
    __syncthreads();
    for (int off = 1; off < 1024; off <<= 1) {
        int add = 0;
        // propagate only within segment: tid<gA implies tid-off<gA
        if (tid >= off && ((tid < gA) || (tid - off >= gA))) add = s[tid - off];
        __syncthreads();
        s[tid] += add;
        __syncthreads();
    }
    if (tid == gA - 1)  *rsA_end = s[tid];   // = E
    if (tid == n - 1)   *rsP_end = s[tid];   // = E
    if (tid < n) partials[tid] = s[tid] - v; // exclusive
}

// pass 3: re-read tile, block-level exclusive scan, write rs and cur
__global__ __launch_bounds__(256) void scan_write_kernel(
        const int* __restrict__ degA, int nA, int* __restrict__ rsA, int* __restrict__ curA,
        const int* __restrict__ degP, int nP, int* __restrict__ rsP, int* __restrict__ curP,
        int gA, const int* __restrict__ partials) {
    const int* deg; int n; int* rs; int* cur;
    int b = blockIdx.x;
    int part = partials[blockIdx.x];
    if (b < gA) { deg = degA; n = nA; rs = rsA; cur = curA; }
    else        { deg = degP; n = nP; rs = rsP; cur = curP; b -= gA; }
    int tid = threadIdx.x;
    int lane = tid & 63, wid = tid >> 6;
    int i0 = b * SCAN_TILE + tid * 4;

    int4 d = make_int4(0, 0, 0, 0);
    if (i0 + 3 < n) {
        d = *(const int4*)(deg + i0);
    } else {
        if (i0 + 0 < n) d.x = deg[i0 + 0];
        if (i0 + 1 < n) d.y = deg[i0 + 1];
        if (i0 + 2 < n) d.z = deg[i0 + 2];
        if (i0 + 3 < n) d.w = deg[i0 + 3];
    }
    int tsum = d.x + d.y + d.z + d.w;

    // wave inclusive scan of thread sums
    int x = tsum;
#pragma unroll
    for (int off = 1; off < 64; off <<= 1) {
        int y = __shfl_up(x, off);
        if (lane >= off) x += y;
    }
    int excl = x - tsum;

    __shared__ int wsum[4];
    if (lane == 63) wsum[wid] = x;
    __syncthreads();
    int woff = 0;
#pragma unroll
    for (int w = 0; w < 4; ++w) if (w < wid) woff += wsum[w];

    int off0 = part + woff + excl;
    int4 o;
    o.x = off0;
    o.y = off0 + d.x;
    o.z = o.y + d.y;
    o.w = o.z + d.z;
    if (i0 + 3 < n) {
        *(int4*)(rs + i0) = o;
        *(int4*)(cur + i0) = o;
    } else {
        if (i0 + 0 < n) { rs[i0 + 0] = o.x; cur[i0 + 0] = o.x; }
        if (i0 + 1 < n) { rs[i0 + 1] = o.y; cur[i0 + 1] = o.y; }
        if (i0 + 2 < n) { rs[i0 + 2] = o.z; cur[i0 + 2] = o.z; }
        if (i0 + 3 < n) { rs[i0 + 3] = o.w; cur[i0 + 3] = o.w; }
    }
}

// ---------------------------------------------------------------------------
// CSR fill via atomic cursors (order within a row is arbitrary; sum is a sum)
// ---------------------------------------------------------------------------
__global__ void csr_fill_kernel(const int* __restrict__ ea, const int* __restrict__ ep, int E,
                                int* __restrict__ curA, int* __restrict__ curP,
                                int* __restrict__ csrA, int* __restrict__ csrP) {
    int stride = gridDim.x * blockDim.x;
    for (int e = blockIdx.x * blockDim.x + threadIdx.x; e < E; e += stride) {
        int a = ea[e], p = ep[e];
        int sa = atomicAdd(&curA[a], 1);
        csrA[sa] = p;
        int sp = atomicAdd(&curP[p], 1);
        csrP[sp] = a;
    }
}

// ---------------------------------------------------------------------------
// pull-mode aggregation: one wave per dst row; lane covers 2 floats.
// ---------------------------------------------------------------------------
__global__ __launch_bounds__(256) void aggregate_kernel(
        const float* __restrict__ xsrc, const int* __restrict__ rs,
        const int* __restrict__ csr, int ndst, float* __restrict__ agg) {
    int gw   = (blockIdx.x * 256 + threadIdx.x) >> 6;
    int lane = threadIdx.x & 63;
    int nw   = (gridDim.x * 256) >> 6;
    for (int d = gw; d < ndst; d += nw) {
        int s0 = rs[d], s1 = rs[d + 1];
        float2 acc = make_float2(0.f, 0.f);
        for (int j = s0; j < s1; ++j) {
            int s = csr[j];
            float2 v = *(const float2*)(xsrc + (size_t)s * D + lane * 2);
            acc.x += v.x; acc.y += v.y;
        }
        *(float2*)(agg + (size_t)d * D + lane * 2) = acc;
    }
}

// ---------------------------------------------------------------------------
// fused node update: out = maybe_relu( xs@Ws + xm@Wm + bs + deg*bm )
// Block: 32 rows x 128 cols; x tiles in LDS; 4x4 register tile per thread.
// out may alias xm (rows are block-exclusive, staged to LDS before writes).
// ---------------------------------------------------------------------------
__global__ __launch_bounds__(256) void fused_linear_kernel(
        const float* __restrict__ xs, const float* xm,
        const float* __restrict__ Ws, const float* __restrict__ Wm,
        const float* __restrict__ bs, const float* __restrict__ bm,
        const int* __restrict__ deg, int relu, float* out) {
    __shared__ float lxs[TR][D];
    __shared__ float lxm[TR][D];
    int tid = threadIdx.x;
    int r_base = blockIdx.x * TR;

    const float4* xs4 = (const float4*)(xs + (size_t)r_base * D);
    const float4* xm4 = (const float4*)(xm + (size_t)r_base * D);
#pragma unroll
    for (int i = 0; i < 4; ++i) {
        int idx = i * 256 + tid;
        int r = idx >> 5, c4 = idx & 31;
        *(float4*)&lxs[r][c4 * 4] = xs4[idx];
        *(float4*)&lxm[r][c4 * 4] = xm4[idx];
    }
    __syncthreads();

    int c0 = (tid & 31) * 4;
    int r0 = (tid >> 5) * 4;
    float acc[4][4] = {};

    for (int k = 0; k < D; k += 2) {
        float4 ws0 = *(const float4*)(Ws + (size_t)k * D + c0);
        float4 ws1 = *(const float4*)(Ws + (size_t)(k + 1) * D + c0);
        float4 wm0 = *(const float4*)(Wm + (size_t)k * D + c0);
        float4 wm1 = *(const float4*)(Wm + (size_t)(k + 1) * D + c0);
#pragma unroll
        for (int i = 0; i < 4; ++i) {
            float2 a = *(const float2*)&lxs[r0 + i][k];
            float2 b = *(const float2*)&lxm[r0 + i][k];
            acc[i][0] += a.x * ws0.x + a.y * ws1.x + b.x * wm0.x + b.y * wm1.x;
            acc[i][1] += a.x * ws0.y + a.y * ws1.y + b.x * wm0.y + b.y * wm1.y;
            acc[i][2] += a.x * ws0.z + a.y * ws1.z + b.x * wm0.z + b.y * wm1.z;
            acc[i][3] += a.x * ws0.w + a.y * ws1.w + b.x * wm0.w + b.y * wm1.w;
        }
    }

    float4 bsv = *(const float4*)(bs + c0);
    float4 bmv = *(const float4*)(bm + c0);
#pragma unroll
    for (int i = 0; i < 4; ++i) {
        int r = r_base + r0 + i;
        float dg = (float)deg[r];
        float4 o;
        o.x = acc[i][0] + bsv.x + dg * bmv.x;
        o.y = acc[i][1] + bsv.y + dg * bmv.y;
        o.z = acc[i][2] + bsv.z + dg * bmv.z;
        o.w = acc[i][3] + bsv.w + dg * bmv.w;
        if (relu) {
            o.x = fmaxf(o.x, 0.f); o.y = fmaxf(o.y, 0.f);
            o.z = fmaxf(o.z, 0.f); o.w = fmaxf(o.w, 0.f);
        }
        *(float4*)(out + (size_t)r * D + c0) = o;
    }
}

// ---------------------------------------------------------------------------
// supervision dot products: one wave per pair, shfl reduction
// ---------------------------------------------------------------------------
__global__ __launch_bounds__(256) void dot_kernel(
        const float* __restrict__ za, const float* __restrict__ zp,
        const int* __restrict__ sa, const int* __restrict__ sp, int S,
        float* __restrict__ out) {
    int gw   = (blockIdx.x * 256 + threadIdx.x) >> 6;
    int lane = threadIdx.x & 63;
    int nw   = (gridDim.x * 256) >> 6;
    for (int i = gw; i < S; i += nw) {
        int a = sa[i], p = sp[i];
        float2 va = *(const float2*)(za + (size_t)a * D + lane * 2);
        float2 vp = *(const float2*)(zp + (size_t)p * D + lane * 2);
        float s = va.x * vp.x + va.y * vp.y;
#pragma unroll
        for (int off = 32; off > 0; off >>= 1) s += __shfl_xor(s, off);
        if (lane == 0) out[i] = s;
    }
}

// ---------------------------------------------------------------------------
extern "C" void kernel_launch(void* const* d_in, const int* in_sizes, int n_in,
                              void* d_out, int out_size, void* d_ws, size_t ws_size,
                              hipStream_t stream) {
    const float* x_a  = (const float*)d_in[0];
    const float* x_p  = (const float*)d_in[1];
    const int*   ea   = (const int*)d_in[2];
    const int*   ep   = (const int*)d_in[3];
    const int*   sa   = (const int*)d_in[4];
    const int*   sp   = (const int*)d_in[5];
    const float* WsA  = (const float*)d_in[6];
    const float* bsA  = (const float*)d_in[7];
    const float* WsP  = (const float*)d_in[8];
    const float* bsP  = (const float*)d_in[9];
    const float* Wa2p = (const float*)d_in[10];
    const float* ba2p = (const float*)d_in[11];
    const float* Wp2a = (const float*)d_in[12];
    const float* bp2a = (const float*)d_in[13];

    const int nA = in_sizes[0] / D;   // 100000
    const int nP = in_sizes[1] / D;   // 200000
    const int E  = in_sizes[2];       // 600000
    const int S  = in_sizes[4];       // 100000

    // ---- workspace layout ----
    char* ws = (char*)d_ws;
    size_t curoff = 0;
    auto alloc = [&](size_t bytes) -> void* {
        void* p = ws + curoff;
        curoff = (curoff + bytes + 255) & ~(size_t)255;
        return p;
    };
    float* agg_a = (float*)alloc((size_t)nA * D * 4);
    float* agg_p = (float*)alloc((size_t)nP * D * 4);
    float* y_a   = (float*)alloc((size_t)nA * D * 4);
    float* y_p   = (float*)alloc((size_t)nP * D * 4);
    int* degA = (int*)alloc((size_t)nA * 4);
    int* degP = (int*)alloc((size_t)nP * 4);
    int* rsA  = (int*)alloc(((size_t)nA + 1) * 4);
    int* rsP  = (int*)alloc(((size_t)nP + 1) * 4);
    int* curA = (int*)alloc((size_t)nA * 4);
    int* curP = (int*)alloc((size_t)nP * 4);
    int* csrA = (int*)alloc((size_t)E * 4);
    int* csrP = (int*)alloc((size_t)E * 4);
    const int gA = (nA + SCAN_TILE - 1) / SCAN_TILE;   // 98
    const int gP = (nP + SCAN_TILE - 1) / SCAN_TILE;   // 196
    int* partials = (int*)alloc((size_t)(gA + gP) * 4);

    // ---- graph preprocessing (reused by both layers) ----
    size_t deg_bytes = (size_t)((char*)degP - (char*)degA) + (size_t)nP * 4;
    hipMemsetAsync(degA, 0, deg_bytes, stream);
    count_deg_kernel<<<1024, 256, 0, stream>>>(ea, ep, E, degA, degP);
    scan_partials_kernel<<<gA + gP, 256, 0, stream>>>(degA, nA, degP, nP, gA, partials);
    scan_block_sums_kernel<<<1, 1024, 0, stream>>>(partials, gA, gP, rsA + nA, rsP + nP);
    scan_write_kernel<<<gA + gP, 256, 0, stream>>>(degA, nA, rsA, curA,
                                                   degP, nP, rsP, curP, gA, partials);
    csr_fill_kernel<<<1024, 256, 0, stream>>>(ea, ep, E, curA, curP, csrA, csrP);

    // ---- layer 0 (relu) ----
    aggregate_kernel<<<(nA + 3) / 4, 256, 0, stream>>>(x_p, rsA, csrA, nA, agg_a);
    aggregate_kernel<<<(nP + 3) / 4, 256, 0, stream>>>(x_a, rsP, csrP, nP, agg_p);
    fused_linear_kernel<<<nA / TR, 256, 0, stream>>>(x_a, agg_a, WsA, Wp2a, bsA, bp2a, degA, 1, y_a);
    fused_linear_kernel<<<nP / TR, 256, 0, stream>>>(x_p, agg_p, WsP, Wa2p, bsP, ba2p, degP, 1, y_p);

    // ---- layer 1 (no relu); matmul writes in-place over agg ----
    aggregate_kernel<<<(nA + 3) / 4, 256, 0, stream>>>(y_p, rsA, csrA, nA, agg_a);
    aggregate_kernel<<<(nP + 3) / 4, 256, 0, stream>>>(y_a, rsP, csrP, nP, agg_p);
    fused_linear_kernel<<<nA / TR, 256, 0, stream>>>(y_a, agg_a, WsA + D * D, Wp2a + D * D,
                                                     bsA + D, bp2a + D, degA, 0, agg_a);
    fused_linear_kernel<<<nP / TR, 256, 0, stream>>>(y_p, agg_p, WsP + D * D, Wa2p + D * D,
                                                     bsP + D, ba2p + D, degP, 0, agg_p);

    // ---- supervision scores ----
    dot_kernel<<<(S + 3) / 4, 256, 0, stream>>>(agg_a, agg_p, sa, sp, S, (float*)d_out);
}

// Round 3
// 850.838 us; speedup vs baseline: 2.0510x; 1.5232x over previous
//
#include <hip/hip_runtime.h>
#include <stdint.h>

#define D 128
#define SCAN_TILE 1024  // elements per scan block (256 thr x 4)

typedef __attribute__((ext_vector_type(8))) short bf16x8_t;
typedef __attribute__((ext_vector_type(4))) float f32x4_t;

__device__ inline unsigned short f2bf(float x) {
    unsigned int u = __float_as_uint(x);
    unsigned int r = (u + 0x7fffu + ((u >> 16) & 1u)) >> 16;   // RNE
    return (unsigned short)r;
}

// ---------------------------------------------------------------------------
// deg histogram (int atomics, ~1.2M total)
// ---------------------------------------------------------------------------
__global__ void count_deg_kernel(const int* __restrict__ ea, const int* __restrict__ ep,
                                 int E, int* __restrict__ degA, int* __restrict__ degP) {
    int stride = gridDim.x * blockDim.x;
    for (int e = blockIdx.x * blockDim.x + threadIdx.x; e < E; e += stride) {
        atomicAdd(&degA[ea[e]], 1);
        atomicAdd(&degP[ep[e]], 1);
    }
}

// ---------------------------------------------------------------------------
// 3-pass device-wide exclusive scan over BOTH deg arrays (unchanged, ~20us)
// ---------------------------------------------------------------------------
__global__ __launch_bounds__(256) void scan_partials_kernel(
        const int* __restrict__ degA, int nA,
        const int* __restrict__ degP, int nP, int gA,
        int* __restrict__ partials) {
    const int* deg; int n;
    int b = blockIdx.x;
    if (b < gA) { deg = degA; n = nA; }
    else        { deg = degP; n = nP; b -= gA; }
    int tid = threadIdx.x;
    int i0 = b * SCAN_TILE + tid * 4;
    int s = 0;
    if (i0 + 3 < n) {
        int4 d = *(const int4*)(deg + i0);
        s = d.x + d.y + d.z + d.w;
    } else {
        for (int j = 0; j < 4; ++j) if (i0 + j < n) s += deg[i0 + j];
    }
#pragma unroll
    for (int off = 32; off; off >>= 1) s += __shfl_xor(s, off);
    __shared__ int wsum[4];
    if ((tid & 63) == 0) wsum[tid >> 6] = s;
    __syncthreads();
    if (tid == 0) partials[blockIdx.x] = wsum[0] + wsum[1] + wsum[2] + wsum[3];
}

__global__ __launch_bounds__(1024) void scan_block_sums_kernel(
        int* __restrict__ partials, int gA, int gP,
        int* __restrict__ rsA_end, int* __restrict__ rsP_end) {
    __shared__ int s[1024];
    int n = gA + gP;
    int tid = threadIdx.x;
    int v = (tid < n) ? partials[tid] : 0;
    s[tid] = v;
    __syncthreads();
    for (int off = 1; off < 1024; off <<= 1) {
        int add = 0;
        if (tid >= off && ((tid < gA) || (tid - off >= gA))) add = s[tid - off];
        __syncthreads();
        s[tid] += add;
        __syncthreads();
    }
    if (tid == gA - 1)  *rsA_end = s[tid];
    if (tid == n - 1)   *rsP_end = s[tid];
    if (tid < n) partials[tid] = s[tid] - v;
}

__global__ __launch_bounds__(256) void scan_write_kernel(
        const int* __restrict__ degA, int nA, int* __restrict__ rsA, int* __restrict__ curA,
        const int* __restrict__ degP, int nP, int* __restrict__ rsP, int* __restrict__ curP,
        int gA, const int* __restrict__ partials) {
    const int* deg; int n; int* rs; int* cur;
    int b = blockIdx.x;
    int part = partials[blockIdx.x];
    if (b < gA) { deg = degA; n = nA; rs = rsA; cur = curA; }
    else        { deg = degP; n = nP; rs = rsP; cur = curP; b -= gA; }
    int tid = threadIdx.x;
    int lane = tid & 63, wid = tid >> 6;
    int i0 = b * SCAN_TILE + tid * 4;

    int4 d = make_int4(0, 0, 0, 0);
    if (i0 + 3 < n) {
        d = *(const int4*)(deg + i0);
    } else {
        if (i0 + 0 < n) d.x = deg[i0 + 0];
        if (i0 + 1 < n) d.y = deg[i0 + 1];
        if (i0 + 2 < n) d.z = deg[i0 + 2];
        if (i0 + 3 < n) d.w = deg[i0 + 3];
    }
    int tsum = d.x + d.y + d.z + d.w;

    int x = tsum;
#pragma unroll
    for (int off = 1; off < 64; off <<= 1) {
        int y = __shfl_up(x, off);
        if (lane >= off) x += y;
    }
    int excl = x - tsum;

    __shared__ int wsum[4];
    if (lane == 63) wsum[wid] = x;
    __syncthreads();
    int woff = 0;
#pragma unroll
    for (int w = 0; w < 4; ++w) if (w < wid) woff += wsum[w];

    int off0 = part + woff + excl;
    int4 o;
    o.x = off0;
    o.y = off0 + d.x;
    o.z = o.y + d.y;
    o.w = o.z + d.z;
    if (i0 + 3 < n) {
        *(int4*)(rs + i0) = o;
        *(int4*)(cur + i0) = o;
    } else {
        if (i0 + 0 < n) { rs[i0 + 0] = o.x; cur[i0 + 0] = o.x; }
        if (i0 + 1 < n) { rs[i0 + 1] = o.y; cur[i0 + 1] = o.y; }
        if (i0 + 2 < n) { rs[i0 + 2] = o.z; cur[i0 + 2] = o.z; }
        if (i0 + 3 < n) { rs[i0 + 3] = o.w; cur[i0 + 3] = o.w; }
    }
}

// ---------------------------------------------------------------------------
// CSR fill via atomic cursors
// ---------------------------------------------------------------------------
__global__ void csr_fill_kernel(const int* __restrict__ ea, const int* __restrict__ ep, int E,
                                int* __restrict__ curA, int* __restrict__ curP,
                                int* __restrict__ csrA, int* __restrict__ csrP) {
    int stride = gridDim.x * blockDim.x;
    for (int e = blockIdx.x * blockDim.x + threadIdx.x; e < E; e += stride) {
        int a = ea[e], p = ep[e];
        int sa = atomicAdd(&curA[a], 1);
        csrA[sa] = p;
        int sp = atomicAdd(&curP[p], 1);
        csrP[sp] = a;
    }
}

// ---------------------------------------------------------------------------
// pull-mode aggregation: one wave per dst row
// ---------------------------------------------------------------------------
__global__ __launch_bounds__(256) void aggregate_kernel(
        const float* __restrict__ xsrc, const int* __restrict__ rs,
        const int* __restrict__ csr, int ndst, float* __restrict__ agg) {
    int gw   = (blockIdx.x * 256 + threadIdx.x) >> 6;
    int lane = threadIdx.x & 63;
    int nw   = (gridDim.x * 256) >> 6;
    for (int d = gw; d < ndst; d += nw) {
        int s0 = rs[d], s1 = rs[d + 1];
        float2 acc = make_float2(0.f, 0.f);
        for (int j = s0; j < s1; ++j) {
            int s = csr[j];
            float2 v = *(const float2*)(xsrc + (size_t)s * D + lane * 2);
            acc.x += v.x; acc.y += v.y;
        }
        *(float2*)(agg + (size_t)d * D + lane * 2) = acc;
    }
}

// ---------------------------------------------------------------------------
// W pre-pack: Bcat = [Ws;Wm] (256x128) -> bf16 MFMA fragment order.
// Fragment f = nf*8 + ks; lane l of frag f holds 8 bf16:
//   B[ks*32 + (l>>4)*8 + j][nf*16 + (l&15)], j=0..7, contiguous 16B.
// combo: 0=A,l0  1=P,l0  2=A,l1  3=P,l1.  grid = 64 blocks x 256 thr.
// ---------------------------------------------------------------------------
__global__ __launch_bounds__(256) void pack_w_kernel(
        const float* __restrict__ WsA, const float* __restrict__ WsP,
        const float* __restrict__ Wa2p, const float* __restrict__ Wp2a,
        unsigned short* __restrict__ Bpack) {
    int combo = blockIdx.x >> 4;
    int e = (blockIdx.x & 15) * 256 + threadIdx.x;   // 0..4095
    int layer = combo >> 1;
    const float* Ws = ((combo & 1) ? WsP : WsA) + (size_t)layer * D * D;
    const float* Wm = ((combo & 1) ? Wa2p : Wp2a) + (size_t)layer * D * D;

    int f = e >> 6, lane = e & 63;
    int nf = f >> 3, ks = f & 7;
    int k0 = ks * 32 + (lane >> 4) * 8;
    int col = nf * 16 + (lane & 15);

    unsigned short v[8];
#pragma unroll
    for (int j = 0; j < 8; ++j) {
        int k = k0 + j;
        float x = (k < D) ? Ws[(size_t)k * D + col] : Wm[(size_t)(k - D) * D + col];
        v[j] = f2bf(x);
    }
    uint4 o;
    o.x = v[0] | ((unsigned)v[1] << 16);
    o.y = v[2] | ((unsigned)v[3] << 16);
    o.z = v[4] | ((unsigned)v[5] << 16);
    o.w = v[6] | ((unsigned)v[7] << 16);
    *(uint4*)(Bpack + (size_t)combo * 32768 + (size_t)e * 8) = o;
}

// ---------------------------------------------------------------------------
// MFMA fused node update: out = maybe_relu([xs|xm] @ Bpack + bs + deg*bm)
// Block = 64 rows x 128 cols, 4 waves (wave w: rows w*16..w*16+15), K=256.
// x staged to LDS as bf16 [64][256] with XOR swizzle byte^=(row&7)<<4
// (kills the 32-way bank conflict of the 512B row stride).
// out may alias xm: all xm reads happen in staging before any store.
// ---------------------------------------------------------------------------
__global__ __launch_bounds__(256) void fused_linear_mfma(
        const float* __restrict__ xs, const float* xm,
        const unsigned short* __restrict__ Bpack,
        const float* __restrict__ bs, const float* __restrict__ bm,
        const int* __restrict__ deg, int relu, int n, float* out) {
    __shared__ uint4 lds4[2048];   // 32 KB
    unsigned char* lds = (unsigned char*)lds4;
    int tid = threadIdx.x;
    int r_base = blockIdx.x * 64;

    // ---- stage x tile (f32 -> bf16, swizzled) ----
#pragma unroll
    for (int i = 0; i < 8; ++i) {
        int c = i * 256 + tid;      // 0..2047 16B-chunks
        int row = c >> 5;           // 0..63
        int kc = (c & 31) * 8;      // 0..248
        int rg = r_base + row;
        uint4 w = make_uint4(0, 0, 0, 0);
        if (rg < n) {
            const float* src = (kc < D) ? (xs + (size_t)rg * D + kc)
                                        : (xm + (size_t)rg * D + (kc - D));
            float4 v0 = *(const float4*)src;
            float4 v1 = *(const float4*)(src + 4);
            w.x = f2bf(v0.x) | ((unsigned)f2bf(v0.y) << 16);
            w.y = f2bf(v0.z) | ((unsigned)f2bf(v0.w) << 16);
            w.z = f2bf(v1.x) | ((unsigned)f2bf(v1.y) << 16);
            w.w = f2bf(v1.z) | ((unsigned)f2bf(v1.w) << 16);
        }
        unsigned addr = ((unsigned)(row * 512 + kc * 2)) ^ ((unsigned)((row & 7) << 4));
        *(uint4*)(lds + addr) = w;
    }
    __syncthreads();

    int wave = tid >> 6, lane = tid & 63;
    int lrow = wave * 16 + (lane & 15);

    // ---- A fragments: a[ks][j] = xcat[lrow][ks*32 + (lane>>4)*8 + j] ----
    bf16x8_t a[8];
#pragma unroll
    for (int ks = 0; ks < 8; ++ks) {
        unsigned addr = ((unsigned)(lrow * 512 + ks * 64 + (lane >> 4) * 16))
                        ^ ((unsigned)((lrow & 7) << 4));
        a[ks] = *(const bf16x8_t*)(lds + addr);
    }

    // ---- MFMA main loop ----
    f32x4_t acc[8];
#pragma unroll
    for (int nf = 0; nf < 8; ++nf) acc[nf] = (f32x4_t){0.f, 0.f, 0.f, 0.f};

    const bf16x8_t* bp = (const bf16x8_t*)Bpack;
#pragma unroll
    for (int nf = 0; nf < 8; ++nf) {
#pragma unroll
        for (int ks = 0; ks < 8; ++ks) {
            bf16x8_t b = bp[(nf * 8 + ks) * 64 + lane];
            acc[nf] = __builtin_amdgcn_mfma_f32_16x16x32_bf16(a[ks], b, acc[nf], 0, 0, 0);
        }
    }

    // ---- epilogue: + bs + deg*bm, relu, store ----
    int rb2 = r_base + wave * 16 + (lane >> 4) * 4;
    float dg[4];
#pragma unroll
    for (int rr = 0; rr < 4; ++rr)
        dg[rr] = (rb2 + rr < n) ? (float)deg[rb2 + rr] : 0.f;

#pragma unroll
    for (int nf = 0; nf < 8; ++nf) {
        int col = nf * 16 + (lane & 15);
        float bsv = bs[col], bmv = bm[col];
#pragma unroll
        for (int rr = 0; rr < 4; ++rr) {
            int r = rb2 + rr;
            if (r < n) {
                float v = acc[nf][rr] + bsv + dg[rr] * bmv;
                if (relu) v = fmaxf(v, 0.f);
                out[(size_t)r * D + col] = v;
            }
        }
    }
}

// ---------------------------------------------------------------------------
// supervision dot products: one wave per pair, shfl reduction
// ---------------------------------------------------------------------------
__global__ __launch_bounds__(256) void dot_kernel(
        const float* __restrict__ za, const float* __restrict__ zp,
        const int* __restrict__ sa, const int* __restrict__ sp, int S,
        float* __restrict__ out) {
    int gw   = (blockIdx.x * 256 + threadIdx.x) >> 6;
    int lane = threadIdx.x & 63;
    int nw   = (gridDim.x * 256) >> 6;
    for (int i = gw; i < S; i += nw) {
        int a = sa[i], p = sp[i];
        float2 va = *(const float2*)(za + (size_t)a * D + lane * 2);
        float2 vp = *(const float2*)(zp + (size_t)p * D + lane * 2);
        float s = va.x * vp.x + va.y * vp.y;
#pragma unroll
        for (int off = 32; off > 0; off >>= 1) s += __shfl_xor(s, off);
        if (lane == 0) out[i] = s;
    }
}

// ---------------------------------------------------------------------------
extern "C" void kernel_launch(void* const* d_in, const int* in_sizes, int n_in,
                              void* d_out, int out_size, void* d_ws, size_t ws_size,
                              hipStream_t stream) {
    const float* x_a  = (const float*)d_in[0];
    const float* x_p  = (const float*)d_in[1];
    const int*   ea   = (const int*)d_in[2];
    const int*   ep   = (const int*)d_in[3];
    const int*   sa   = (const int*)d_in[4];
    const int*   sp   = (const int*)d_in[5];
    const float* WsA  = (const float*)d_in[6];
    const float* bsA  = (const float*)d_in[7];
    const float* WsP  = (const float*)d_in[8];
    const float* bsP  = (const float*)d_in[9];
    const float* Wa2p = (const float*)d_in[10];
    const float* ba2p = (const float*)d_in[11];
    const float* Wp2a = (const float*)d_in[12];
    const float* bp2a = (const float*)d_in[13];

    const int nA = in_sizes[0] / D;   // 100000
    const int nP = in_sizes[1] / D;   // 200000
    const int E  = in_sizes[2];       // 600000
    const int S  = in_sizes[4];       // 100000

    // ---- workspace layout ----
    char* ws = (char*)d_ws;
    size_t curoff = 0;
    auto alloc = [&](size_t bytes) -> void* {
        void* p = ws + curoff;
        curoff = (curoff + bytes + 255) & ~(size_t)255;
        return p;
    };
    float* agg_a = (float*)alloc((size_t)nA * D * 4);
    float* agg_p = (float*)alloc((size_t)nP * D * 4);
    float* y_a   = (float*)alloc((size_t)nA * D * 4);
    float* y_p   = (float*)alloc((size_t)nP * D * 4);
    int* degA = (int*)alloc((size_t)nA * 4);
    int* degP = (int*)alloc((size_t)nP * 4);
    int* rsA  = (int*)alloc(((size_t)nA + 1) * 4);
    int* rsP  = (int*)alloc(((size_t)nP + 1) * 4);
    int* curA = (int*)alloc((size_t)nA * 4);
    int* curP = (int*)alloc((size_t)nP * 4);
    int* csrA = (int*)alloc((size_t)E * 4);
    int* csrP = (int*)alloc((size_t)E * 4);
    const int gA = (nA + SCAN_TILE - 1) / SCAN_TILE;
    const int gP = (nP + SCAN_TILE - 1) / SCAN_TILE;
    int* partials = (int*)alloc((size_t)(gA + gP) * 4);
    unsigned short* Bpack = (unsigned short*)alloc((size_t)4 * 32768 * 2);  // 256 KB

    // ---- graph preprocessing + W packing ----
    size_t deg_bytes = (size_t)((char*)degP - (char*)degA) + (size_t)nP * 4;
    hipMemsetAsync(degA, 0, deg_bytes, stream);
    pack_w_kernel<<<64, 256, 0, stream>>>(WsA, WsP, Wa2p, Wp2a, Bpack);
    count_deg_kernel<<<1024, 256, 0, stream>>>(ea, ep, E, degA, degP);
    scan_partials_kernel<<<gA + gP, 256, 0, stream>>>(degA, nA, degP, nP, gA, partials);
    scan_block_sums_kernel<<<1, 1024, 0, stream>>>(partials, gA, gP, rsA + nA, rsP + nP);
    scan_write_kernel<<<gA + gP, 256, 0, stream>>>(degA, nA, rsA, curA,
                                                   degP, nP, rsP, curP, gA, partials);
    csr_fill_kernel<<<1024, 256, 0, stream>>>(ea, ep, E, curA, curP, csrA, csrP);

    const int gmA = (nA + 63) / 64;   // 1563 (tail-guarded)
    const int gmP = (nP + 63) / 64;   // 3125

    // ---- layer 0 (relu) ----
    aggregate_kernel<<<(nA + 3) / 4, 256, 0, stream>>>(x_p, rsA, csrA, nA, agg_a);
    aggregate_kernel<<<(nP + 3) / 4, 256, 0, stream>>>(x_a, rsP, csrP, nP, agg_p);
    fused_linear_mfma<<<gmA, 256, 0, stream>>>(x_a, agg_a, Bpack + 0 * 32768,
                                               bsA, bp2a, degA, 1, nA, y_a);
    fused_linear_mfma<<<gmP, 256, 0, stream>>>(x_p, agg_p, Bpack + 1 * 32768,
                                               bsP, ba2p, degP, 1, nP, y_p);

    // ---- layer 1 (no relu); writes in-place over agg ----
    aggregate_kernel<<<(nA + 3) / 4, 256, 0, stream>>>(y_p, rsA, csrA, nA, agg_a);
    aggregate_kernel<<<(nP + 3) / 4, 256, 0, stream>>>(y_a, rsP, csrP, nP, agg_p);
    fused_linear_mfma<<<gmA, 256, 0, stream>>>(y_a, agg_a, Bpack + 2 * 32768,
                                               bsA + D, bp2a + D, degA, 0, nA, agg_a);
    fused_linear_mfma<<<gmP, 256, 0, stream>>>(y_p, agg_p, Bpack + 3 * 32768,
                                               bsP + D, ba2p + D, degP, 0, nP, agg_p);

    // ---- supervision scores ----
    dot_kernel<<<(S + 3) / 4, 256, 0, stream>>>(agg_a, agg_p, sa, sp, S, (float*)d_out);
}